// Round 4
// baseline (280.042 us; speedup 1.0000x reference)
//
#include <hip/hip_runtime.h>
#include <math.h>

#define N_ROWS 262144
#define DIM 64
#define K_CODES 1024
#define NT 32                 // code tiles of 32
#define ROWS_PER_BLOCK 128
#define EPSF 1e-12f

typedef _Float16 f16x8 __attribute__((ext_vector_type(8)));
typedef float f32x16 __attribute__((ext_vector_type(16)));

// ws layout (floats):
//   wn      : [0, 65536)          normalized codebook fp32 (for gather/epilogue)
//   msw     : [65536, 66560)      -0.5 * sum(wn^2) per code
//   partial : [66560, 68608)      per-block loss partials
//   wf      : halves after that   codebook hi/lo f16, 32x32x16 B-fragment order
//             [tile t][h][kstep s][lane][i]  : half = t*4096 + h*2048 + s*512 + lane*8 + i

__global__ __launch_bounds__(64) void prep_codebook(
    const float* __restrict__ w, float* __restrict__ wn,
    float* __restrict__ msw, _Float16* __restrict__ wf)
{
    int k = blockIdx.x;
    int d = threadIdx.x;
    float v = w[k * DIM + d];
    float sq = v * v;
    #pragma unroll
    for (int off = 32; off; off >>= 1) sq += __shfl_xor(sq, off, 64);
    float n = fmaxf(sqrtf(sq), EPSF);
    float o = v / n;
    wn[k * DIM + d] = o;
    float s2 = o * o;
    #pragma unroll
    for (int off = 32; off; off >>= 1) s2 += __shfl_xor(s2, off, 64);
    if (d == 0) msw[k] = -0.5f * s2;

    _Float16 hi = (_Float16)o;
    _Float16 lo = (_Float16)(o - (float)hi);
    // B fragment for 32x32x16: lane = g*32 + n holds dims d = s*16 + g*8 + i of code n
    int t = k >> 5, nn = k & 31, s = d >> 4, g = (d >> 3) & 1, i = d & 7;
    size_t base = (size_t)t * 4096 + (size_t)s * 512 + (size_t)(g * 32 + nn) * 8 + i;
    wf[base] = hi;           // h = 0
    wf[base + 2048] = lo;    // h = 1
}

// Body for one 32-code tile. Compare of previous tile's accs is done at the
// top (fills the lgkmcnt wait); two independent depth-6 MFMA chains give the
// matrix pipe ILP 2; staging writes are 16B/thread chunks (conflict-free).
#define BODY(T, CW0, CW1, NL0, NL1)                                           \
  {                                                                           \
    const int cur = (T) & 1;                                                  \
    const _Float16* bp = &bbuf[cur][lane * 8];                                \
    f16x8 bh0 = *(const f16x8*)(bp);                                          \
    f16x8 bh1 = *(const f16x8*)(bp + 512);                                    \
    f16x8 bh2 = *(const f16x8*)(bp + 1024);                                   \
    f16x8 bh3 = *(const f16x8*)(bp + 1536);                                   \
    f16x8 bl0 = *(const f16x8*)(bp + 2048);                                   \
    f16x8 bl1 = *(const f16x8*)(bp + 2560);                                   \
    f16x8 bl2 = *(const f16x8*)(bp + 3072);                                   \
    f16x8 bl3 = *(const f16x8*)(bp + 3584);                                   \
    float mval = msw_lds[(T) * 32 + col];                                     \
    if ((T) + 1 < NT) {                                                       \
      f16x8* wb = (f16x8*)&bbuf[cur ^ 1][0];                                  \
      wb[tid] = CW0;                                                          \
      wb[tid + 256] = CW1;                                                    \
    }                                                                         \
    if ((T) + 2 < NT) {                                                       \
      NL0 = wf8[((T) + 2) * 512 + tid];                                       \
      NL1 = wf8[((T) + 2) * 512 + 256 + tid];                                 \
    }                                                                         \
    if ((T) > 0) {                                                            \
      _Pragma("unroll")                                                       \
      for (int e = 0; e < 16; ++e) {                                          \
        float s = acc0[e] + acc1[e];                                          \
        if (s > best[e]) { best[e] = s; bt[e] = (T) - 1; }                    \
      }                                                                       \
    }                                                                         \
    _Pragma("unroll")                                                         \
    for (int e = 0; e < 16; ++e) { acc0[e] = mval; acc1[e] = 0.f; }           \
    acc0 = __builtin_amdgcn_mfma_f32_32x32x16_f16(ah[0], bh0, acc0, 0, 0, 0); \
    acc1 = __builtin_amdgcn_mfma_f32_32x32x16_f16(ah[0], bl0, acc1, 0, 0, 0); \
    acc0 = __builtin_amdgcn_mfma_f32_32x32x16_f16(ah[1], bh1, acc0, 0, 0, 0); \
    acc1 = __builtin_amdgcn_mfma_f32_32x32x16_f16(ah[1], bl1, acc1, 0, 0, 0); \
    acc0 = __builtin_amdgcn_mfma_f32_32x32x16_f16(ah[2], bh2, acc0, 0, 0, 0); \
    acc1 = __builtin_amdgcn_mfma_f32_32x32x16_f16(ah[2], bl2, acc1, 0, 0, 0); \
    acc0 = __builtin_amdgcn_mfma_f32_32x32x16_f16(ah[3], bh3, acc0, 0, 0, 0); \
    acc1 = __builtin_amdgcn_mfma_f32_32x32x16_f16(ah[3], bl3, acc1, 0, 0, 0); \
    acc0 = __builtin_amdgcn_mfma_f32_32x32x16_f16(al[0], bh0, acc0, 0, 0, 0); \
    acc1 = __builtin_amdgcn_mfma_f32_32x32x16_f16(al[2], bh2, acc1, 0, 0, 0); \
    acc0 = __builtin_amdgcn_mfma_f32_32x32x16_f16(al[1], bh1, acc0, 0, 0, 0); \
    acc1 = __builtin_amdgcn_mfma_f32_32x32x16_f16(al[3], bh3, acc1, 0, 0, 0); \
    __syncthreads();                                                          \
  }

__global__ __launch_bounds__(256, 3) void vq_main_kernel(
    const float* __restrict__ x,
    const float* __restrict__ wn,
    const float* __restrict__ msw,
    const _Float16* __restrict__ wf,
    float* __restrict__ out_q,
    float* __restrict__ out_idx,
    float* __restrict__ partial)
{
    __shared__ _Float16 bbuf[2][4096];          // 2 x 8 KB code tiles
    __shared__ float msw_lds[K_CODES];
    __shared__ int idx_lds[ROWS_PER_BLOCK];
    __shared__ float inv_lds[ROWS_PER_BLOCK];
    __shared__ float red[4];

    const int tid = threadIdx.x;
    const int wv = tid >> 6;
    const int lane = tid & 63;
    const int col = lane & 31;
    const int g = lane >> 5;
    const int block_row0 = blockIdx.x * ROWS_PER_BLOCK;

    // ---- prologue: load + normalize 32 rows/wave, build hi/lo A-fragments ----
    // A for 32x32x16: lane holds A[m=lane&31][k=(lane>>5)*8+i], kstep s → dims s*16+g*8+i
    f16x8 ah[4], al[4];
    {
        const int arow = block_row0 + wv * 32 + col;
        const float* xrow = x + (size_t)arow * DIM + g * 8;
        float xv[4][8];
        #pragma unroll
        for (int s = 0; s < 4; ++s) {
            float4 q0 = *(const float4*)(xrow + s * 16);
            float4 q1 = *(const float4*)(xrow + s * 16 + 4);
            xv[s][0] = q0.x; xv[s][1] = q0.y; xv[s][2] = q0.z; xv[s][3] = q0.w;
            xv[s][4] = q1.x; xv[s][5] = q1.y; xv[s][6] = q1.z; xv[s][7] = q1.w;
        }
        float ss = 0.f;
        #pragma unroll
        for (int s = 0; s < 4; ++s)
            #pragma unroll
            for (int i = 0; i < 8; ++i) ss += xv[s][i] * xv[s][i];
        ss += __shfl_xor(ss, 32, 64);   // partner lane holds the row's other 32 dims
        float nrm = fmaxf(sqrtf(ss), EPSF);
        float inv = 1.0f / nrm;
        if (g == 0) inv_lds[wv * 32 + col] = inv;
        #pragma unroll
        for (int s = 0; s < 4; ++s)
            #pragma unroll
            for (int i = 0; i < 8; ++i) {
                float v = xv[s][i] * inv;
                _Float16 hi = (_Float16)v;
                ah[s][i] = hi;
                al[s][i] = (_Float16)(v - (float)hi);
            }
    }

    // ---- stage msw into LDS ----
    {
        float4 mv = *(const float4*)(msw + tid * 4);
        *(float4*)&msw_lds[tid * 4] = mv;
    }

    // ---- staging prologue: tile 0 → bbuf[0]; tile 1 → regs ----
    const f16x8* wf8 = (const f16x8*)wf;
    f16x8 sA0, sA1, sB0, sB1;
    sB0 = wf8[tid];
    sB1 = wf8[256 + tid];
    {
        f16x8* wb = (f16x8*)&bbuf[0][0];
        wb[tid] = sB0;
        wb[tid + 256] = sB1;
    }
    sA0 = wf8[512 + tid];
    sA1 = wf8[512 + 256 + tid];
    __syncthreads();

    float best[16];
    int bt[16];
    #pragma unroll
    for (int e = 0; e < 16; ++e) { best[e] = -3.4e38f; bt[e] = 0; }
    f32x16 acc0, acc1;

    // ---- main loop: 32 code tiles, double-buffered, compare deferred 1 tile ----
    for (int tt = 0; tt < NT; tt += 2) {
        BODY(tt, sA0, sA1, sB0, sB1)
        BODY(tt + 1, sB0, sB1, sA0, sA1)
    }
    // final compare for tile NT-1
    #pragma unroll
    for (int e = 0; e < 16; ++e) {
        float s = acc0[e] + acc1[e];
        if (s > best[e]) { best[e] = s; bt[e] = NT - 1; }
    }

    // ---- argmax reduce across the 32 lanes holding each row ----
    // C/D 32x32: col = lane&31, row = (e&3) + 8*(e>>2) + 4*(lane>>5)
    #pragma unroll
    for (int e = 0; e < 16; ++e) {
        float b = best[e];
        int bi = bt[e] * 32 + col;
        #pragma unroll
        for (int off = 1; off <= 16; off <<= 1) {
            float ob = __shfl_xor(b, off, 64);
            int oi = __shfl_xor(bi, off, 64);
            if (ob > b || (ob == b && oi < bi)) { b = ob; bi = oi; }
        }
        if (col == 0)
            idx_lds[wv * 32 + (e & 3) + 8 * (e >> 2) + 4 * g] = bi;
    }
    __syncthreads();

    // ---- epilogue: gather fp32 codebook row, write out, loss partial ----
    const int lr = tid >> 1;
    const int grow = block_row0 + lr;
    const int d0 = (tid & 1) * 32;
    const int ci = idx_lds[lr];
    const float invn = inv_lds[lr];
    const float4* xp = (const float4*)(x + (size_t)grow * DIM + d0);
    const float4* qp = (const float4*)(wn + (size_t)ci * DIM + d0);
    float4* op = (float4*)(out_q + (size_t)grow * DIM + d0);
    float ls = 0.f;
    #pragma unroll
    for (int i = 0; i < 8; ++i) {
        float4 qv = qp[i];
        float4 xv4 = xp[i];
        float e0 = qv.x - xv4.x * invn;
        float e1 = qv.y - xv4.y * invn;
        float e2 = qv.z - xv4.z * invn;
        float e3 = qv.w - xv4.w * invn;
        ls += e0 * e0 + e1 * e1 + e2 * e2 + e3 * e3;
        op[i] = qv;
    }
    if (!(tid & 1)) out_idx[grow] = (float)ci;

    float s = ls;
    #pragma unroll
    for (int off = 32; off; off >>= 1) s += __shfl_xor(s, off, 64);
    if (lane == 0) red[wv] = s;
    __syncthreads();
    if (tid == 0) partial[blockIdx.x] = (red[0] + red[1]) + (red[2] + red[3]);
}

__global__ __launch_bounds__(256) void finalize_kernel(
    const float* __restrict__ partial, float* __restrict__ loss_out)
{
    __shared__ float red[4];
    int t = threadIdx.x;
    float s = 0.f;
    #pragma unroll
    for (int i = 0; i < 8; ++i) s += partial[t * 8 + i];  // fixed order
    #pragma unroll
    for (int off = 32; off; off >>= 1) s += __shfl_xor(s, off, 64);
    if ((t & 63) == 0) red[t >> 6] = s;
    __syncthreads();
    if (t == 0)
        *loss_out = 1.25f * (((red[0] + red[1]) + (red[2] + red[3]))
                             / (float)((size_t)N_ROWS * DIM));
}

extern "C" void kernel_launch(void* const* d_in, const int* in_sizes, int n_in,
                              void* d_out, int out_size, void* d_ws, size_t ws_size,
                              hipStream_t stream) {
    const float* x = (const float*)d_in[0];   // [N, D]
    const float* w = (const float*)d_in[1];   // [K, D]
    float* out = (float*)d_out;
    float* ws = (float*)d_ws;

    float* wn      = ws;                                   // 65536 floats
    float* msw     = wn + (size_t)K_CODES * DIM;           // 1024 floats
    float* partial = msw + K_CODES;                        // 2048 floats
    _Float16* wf   = (_Float16*)(partial + 2048);          // 131072 halves (256 KB)

    float* out_q    = out;                                 // [N*D]
    float* out_loss = out + (size_t)N_ROWS * DIM;          // [1]
    float* out_idx  = out_loss + 1;                        // [N]

    prep_codebook<<<K_CODES, 64, 0, stream>>>(w, wn, msw, wf);
    vq_main_kernel<<<N_ROWS / ROWS_PER_BLOCK, 256, 0, stream>>>(
        x, wn, msw, wf, out_q, out_idx, partial);
    finalize_kernel<<<1, 256, 0, stream>>>(partial, out_loss);
}

// Round 5
// 147.118 us; speedup vs baseline: 1.9035x; 1.9035x over previous
//
#include <hip/hip_runtime.h>
#include <math.h>

#define N_ROWS 262144
#define DIM 64
#define K_CODES 1024
#define NT 32                 // code tiles of 32
#define ROWS_PER_BLOCK 256
#define EPSF 1e-12f

typedef _Float16 f16x8 __attribute__((ext_vector_type(8)));
typedef float f32x16 __attribute__((ext_vector_type(16)));

// ws layout (floats):
//   wn      : [0, 65536)          normalized codebook fp32 (for gather/epilogue)
//   msw     : [65536, 66560)      -0.5 * sum(wn^2) per code
//   partial : [66560, 67584)      per-block loss partials (1024)
//   wf      : halves after that   codebook hi/lo f16, 32x32x16 B-fragment order
//             [tile t][h][kstep s][lane][i] : half = t*4096 + h*2048 + s*512 + lane*8 + i

__global__ __launch_bounds__(64) void prep_codebook(
    const float* __restrict__ w, float* __restrict__ wn,
    float* __restrict__ msw, _Float16* __restrict__ wf)
{
    int k = blockIdx.x;
    int d = threadIdx.x;
    float v = w[k * DIM + d];
    float sq = v * v;
    #pragma unroll
    for (int off = 32; off; off >>= 1) sq += __shfl_xor(sq, off, 64);
    float n = fmaxf(sqrtf(sq), EPSF);
    float o = v / n;
    wn[k * DIM + d] = o;
    float s2 = o * o;
    #pragma unroll
    for (int off = 32; off; off >>= 1) s2 += __shfl_xor(s2, off, 64);
    if (d == 0) msw[k] = -0.5f * s2;

    _Float16 hi = (_Float16)o;
    _Float16 lo = (_Float16)(o - (float)hi);
    // B fragment for 32x32x16: lane = g*32 + n holds dims d = s*16 + g*8 + i of code n
    int t = k >> 5, nn = k & 31, s = d >> 4, g = (d >> 3) & 1, i = d & 7;
    size_t base = (size_t)t * 4096 + (size_t)s * 512 + (size_t)(g * 32 + nn) * 8 + i;
    wf[base] = hi;           // h = 0
    wf[base + 2048] = lo;    // h = 1
}

// One 32-code tile: 8 shared B-fragment reads feed 24 MFMAs in two
// independent 12-chains (row-tile 0 and row-tile 1). Compare immediately
// (no acc live across the barrier). Staging: 16B/thread chunks, conflict-free.
#define BODY(T, CW0, CW1, NL0, NL1)                                           \
  {                                                                           \
    const int cur = (T) & 1;                                                  \
    const _Float16* bp = &bbuf[cur][lane * 8];                                \
    f16x8 bh0 = *(const f16x8*)(bp);                                          \
    f16x8 bh1 = *(const f16x8*)(bp + 512);                                    \
    f16x8 bh2 = *(const f16x8*)(bp + 1024);                                   \
    f16x8 bh3 = *(const f16x8*)(bp + 1536);                                   \
    f16x8 bl0 = *(const f16x8*)(bp + 2048);                                   \
    f16x8 bl1 = *(const f16x8*)(bp + 2560);                                   \
    f16x8 bl2 = *(const f16x8*)(bp + 3072);                                   \
    f16x8 bl3 = *(const f16x8*)(bp + 3584);                                   \
    float mval = msw_lds[(T) * 32 + col];                                     \
    if ((T) + 1 < NT) {                                                       \
      f16x8* wb = (f16x8*)&bbuf[cur ^ 1][0];                                  \
      wb[tid] = CW0;                                                          \
      wb[tid + 256] = CW1;                                                    \
    }                                                                         \
    if ((T) + 2 < NT) {                                                       \
      NL0 = wf8[((T) + 2) * 512 + tid];                                       \
      NL1 = wf8[((T) + 2) * 512 + 256 + tid];                                 \
    }                                                                         \
    f32x16 acc0, acc1;                                                        \
    _Pragma("unroll")                                                         \
    for (int e = 0; e < 16; ++e) { acc0[e] = mval; acc1[e] = mval; }          \
    acc0 = __builtin_amdgcn_mfma_f32_32x32x16_f16(ah[0][0], bh0, acc0, 0, 0, 0); \
    acc1 = __builtin_amdgcn_mfma_f32_32x32x16_f16(ah[1][0], bh0, acc1, 0, 0, 0); \
    acc0 = __builtin_amdgcn_mfma_f32_32x32x16_f16(ah[0][1], bh1, acc0, 0, 0, 0); \
    acc1 = __builtin_amdgcn_mfma_f32_32x32x16_f16(ah[1][1], bh1, acc1, 0, 0, 0); \
    acc0 = __builtin_amdgcn_mfma_f32_32x32x16_f16(ah[0][2], bh2, acc0, 0, 0, 0); \
    acc1 = __builtin_amdgcn_mfma_f32_32x32x16_f16(ah[1][2], bh2, acc1, 0, 0, 0); \
    acc0 = __builtin_amdgcn_mfma_f32_32x32x16_f16(ah[0][3], bh3, acc0, 0, 0, 0); \
    acc1 = __builtin_amdgcn_mfma_f32_32x32x16_f16(ah[1][3], bh3, acc1, 0, 0, 0); \
    acc0 = __builtin_amdgcn_mfma_f32_32x32x16_f16(al[0][0], bh0, acc0, 0, 0, 0); \
    acc1 = __builtin_amdgcn_mfma_f32_32x32x16_f16(al[1][0], bh0, acc1, 0, 0, 0); \
    acc0 = __builtin_amdgcn_mfma_f32_32x32x16_f16(al[0][1], bh1, acc0, 0, 0, 0); \
    acc1 = __builtin_amdgcn_mfma_f32_32x32x16_f16(al[1][1], bh1, acc1, 0, 0, 0); \
    acc0 = __builtin_amdgcn_mfma_f32_32x32x16_f16(al[0][2], bh2, acc0, 0, 0, 0); \
    acc1 = __builtin_amdgcn_mfma_f32_32x32x16_f16(al[1][2], bh2, acc1, 0, 0, 0); \
    acc0 = __builtin_amdgcn_mfma_f32_32x32x16_f16(al[0][3], bh3, acc0, 0, 0, 0); \
    acc1 = __builtin_amdgcn_mfma_f32_32x32x16_f16(al[1][3], bh3, acc1, 0, 0, 0); \
    acc0 = __builtin_amdgcn_mfma_f32_32x32x16_f16(ah[0][0], bl0, acc0, 0, 0, 0); \
    acc1 = __builtin_amdgcn_mfma_f32_32x32x16_f16(ah[1][0], bl0, acc1, 0, 0, 0); \
    acc0 = __builtin_amdgcn_mfma_f32_32x32x16_f16(ah[0][1], bl1, acc0, 0, 0, 0); \
    acc1 = __builtin_amdgcn_mfma_f32_32x32x16_f16(ah[1][1], bl1, acc1, 0, 0, 0); \
    acc0 = __builtin_amdgcn_mfma_f32_32x32x16_f16(ah[0][2], bl2, acc0, 0, 0, 0); \
    acc1 = __builtin_amdgcn_mfma_f32_32x32x16_f16(ah[1][2], bl2, acc1, 0, 0, 0); \
    acc0 = __builtin_amdgcn_mfma_f32_32x32x16_f16(ah[0][3], bl3, acc0, 0, 0, 0); \
    acc1 = __builtin_amdgcn_mfma_f32_32x32x16_f16(ah[1][3], bl3, acc1, 0, 0, 0); \
    _Pragma("unroll")                                                         \
    for (int e = 0; e < 16; ++e) {                                            \
      if (acc0[e] > best0[e]) { best0[e] = acc0[e]; bt0[e] = (T); }           \
      if (acc1[e] > best1[e]) { best1[e] = acc1[e]; bt1[e] = (T); }           \
    }                                                                         \
    __syncthreads();                                                          \
  }

__global__ __launch_bounds__(256, 2) void vq_main_kernel(
    const float* __restrict__ x,
    const float* __restrict__ wn,
    const float* __restrict__ msw,
    const _Float16* __restrict__ wf,
    float* __restrict__ out_q,
    float* __restrict__ out_idx,
    float* __restrict__ partial)
{
    __shared__ _Float16 bbuf[2][4096];          // 2 x 8 KB code tiles
    __shared__ float msw_lds[K_CODES];
    __shared__ int idx_lds[ROWS_PER_BLOCK];
    __shared__ float inv_lds[ROWS_PER_BLOCK];
    __shared__ float red[4];

    const int tid = threadIdx.x;
    const int wv = tid >> 6;
    const int lane = tid & 63;
    const int col = lane & 31;
    const int g = lane >> 5;
    const int block_row0 = blockIdx.x * ROWS_PER_BLOCK;

    // ---- prologue: 64 rows/wave (2 row-tiles), normalize, hi/lo A-fragments ----
    // A for 32x32x16: lane holds A[m=lane&31][k=(lane>>5)*8+i], kstep s → dims s*16+g*8+i
    f16x8 ah[2][4], al[2][4];
    #pragma unroll
    for (int rt = 0; rt < 2; ++rt) {
        const int arow = block_row0 + wv * 64 + rt * 32 + col;
        const float* xrow = x + (size_t)arow * DIM + g * 8;
        float xv[4][8];
        #pragma unroll
        for (int s = 0; s < 4; ++s) {
            float4 q0 = *(const float4*)(xrow + s * 16);
            float4 q1 = *(const float4*)(xrow + s * 16 + 4);
            xv[s][0] = q0.x; xv[s][1] = q0.y; xv[s][2] = q0.z; xv[s][3] = q0.w;
            xv[s][4] = q1.x; xv[s][5] = q1.y; xv[s][6] = q1.z; xv[s][7] = q1.w;
        }
        float ss = 0.f;
        #pragma unroll
        for (int s = 0; s < 4; ++s)
            #pragma unroll
            for (int i = 0; i < 8; ++i) ss += xv[s][i] * xv[s][i];
        ss += __shfl_xor(ss, 32, 64);   // partner lane holds the row's other 32 dims
        float nrm = fmaxf(sqrtf(ss), EPSF);
        float inv = 1.0f / nrm;
        if (g == 0) inv_lds[wv * 64 + rt * 32 + col] = inv;
        #pragma unroll
        for (int s = 0; s < 4; ++s)
            #pragma unroll
            for (int i = 0; i < 8; ++i) {
                float v = xv[s][i] * inv;
                _Float16 hi = (_Float16)v;
                ah[rt][s][i] = hi;
                al[rt][s][i] = (_Float16)(v - (float)hi);
            }
    }

    // ---- stage msw into LDS ----
    {
        float4 mv = *(const float4*)(msw + tid * 4);
        *(float4*)&msw_lds[tid * 4] = mv;
    }

    // ---- staging prologue: tile 0 → bbuf[0]; tile 1 → regs ----
    const f16x8* wf8 = (const f16x8*)wf;
    f16x8 sA0, sA1, sB0, sB1;
    sB0 = wf8[tid];
    sB1 = wf8[256 + tid];
    {
        f16x8* wb = (f16x8*)&bbuf[0][0];
        wb[tid] = sB0;
        wb[tid + 256] = sB1;
    }
    sA0 = wf8[512 + tid];
    sA1 = wf8[512 + 256 + tid];
    __syncthreads();

    float best0[16], best1[16];
    int bt0[16], bt1[16];
    #pragma unroll
    for (int e = 0; e < 16; ++e) {
        best0[e] = -3.4e38f; bt0[e] = 0;
        best1[e] = -3.4e38f; bt1[e] = 0;
    }

    // ---- main loop: 32 code tiles, double-buffered ----
    for (int tt = 0; tt < NT; tt += 2) {
        BODY(tt, sA0, sA1, sB0, sB1)
        BODY(tt + 1, sB0, sB1, sA0, sA1)
    }

    // ---- argmax reduce across the 32 lanes holding each row ----
    // C/D 32x32: col = lane&31, row = (e&3) + 8*(e>>2) + 4*(lane>>5)
    #pragma unroll
    for (int e = 0; e < 16; ++e) {
        float b0 = best0[e];
        int bi0 = bt0[e] * 32 + col;
        float b1 = best1[e];
        int bi1 = bt1[e] * 32 + col;
        #pragma unroll
        for (int off = 1; off <= 16; off <<= 1) {
            float ob = __shfl_xor(b0, off, 64);
            int oi = __shfl_xor(bi0, off, 64);
            if (ob > b0 || (ob == b0 && oi < bi0)) { b0 = ob; bi0 = oi; }
            float ob1 = __shfl_xor(b1, off, 64);
            int oi1 = __shfl_xor(bi1, off, 64);
            if (ob1 > b1 || (ob1 == b1 && oi1 < bi1)) { b1 = ob1; bi1 = oi1; }
        }
        if (col == 0) {
            const int rbase = wv * 64 + (e & 3) + 8 * (e >> 2) + 4 * g;
            idx_lds[rbase] = bi0;
            idx_lds[rbase + 32] = bi1;
        }
    }
    __syncthreads();

    // ---- epilogue: gather fp32 codebook rows, write out, loss partial ----
    float ls = 0.f;
    #pragma unroll
    for (int rep = 0; rep < 2; ++rep) {
        const int lr = rep * 128 + (tid >> 1);
        const int grow = block_row0 + lr;
        const int d0 = (tid & 1) * 32;
        const int ci = idx_lds[lr];
        const float invn = inv_lds[lr];
        const float4* xp = (const float4*)(x + (size_t)grow * DIM + d0);
        const float4* qp = (const float4*)(wn + (size_t)ci * DIM + d0);
        float4* op = (float4*)(out_q + (size_t)grow * DIM + d0);
        #pragma unroll
        for (int i = 0; i < 8; ++i) {
            float4 qv = qp[i];
            float4 xv4 = xp[i];
            float e0 = qv.x - xv4.x * invn;
            float e1 = qv.y - xv4.y * invn;
            float e2 = qv.z - xv4.z * invn;
            float e3 = qv.w - xv4.w * invn;
            ls += e0 * e0 + e1 * e1 + e2 * e2 + e3 * e3;
            op[i] = qv;
        }
        if (!(tid & 1)) out_idx[grow] = (float)ci;
    }

    float s = ls;
    #pragma unroll
    for (int off = 32; off; off >>= 1) s += __shfl_xor(s, off, 64);
    if (lane == 0) red[wv] = s;
    __syncthreads();
    if (tid == 0) partial[blockIdx.x] = (red[0] + red[1]) + (red[2] + red[3]);
}

__global__ __launch_bounds__(256) void finalize_kernel(
    const float* __restrict__ partial, float* __restrict__ loss_out)
{
    __shared__ float red[4];
    int t = threadIdx.x;
    float s = 0.f;
    #pragma unroll
    for (int i = 0; i < 4; ++i) s += partial[t * 4 + i];  // fixed order
    #pragma unroll
    for (int off = 32; off; off >>= 1) s += __shfl_xor(s, off, 64);
    if ((t & 63) == 0) red[t >> 6] = s;
    __syncthreads();
    if (t == 0)
        *loss_out = 1.25f * (((red[0] + red[1]) + (red[2] + red[3]))
                             / (float)((size_t)N_ROWS * DIM));
}

extern "C" void kernel_launch(void* const* d_in, const int* in_sizes, int n_in,
                              void* d_out, int out_size, void* d_ws, size_t ws_size,
                              hipStream_t stream) {
    const float* x = (const float*)d_in[0];   // [N, D]
    const float* w = (const float*)d_in[1];   // [K, D]
    float* out = (float*)d_out;
    float* ws = (float*)d_ws;

    float* wn      = ws;                                   // 65536 floats
    float* msw     = wn + (size_t)K_CODES * DIM;           // 1024 floats
    float* partial = msw + K_CODES;                        // 1024 floats
    _Float16* wf   = (_Float16*)(partial + 1024);          // 131072 halves (256 KB)

    float* out_q    = out;                                 // [N*D]
    float* out_loss = out + (size_t)N_ROWS * DIM;          // [1]
    float* out_idx  = out_loss + 1;                        // [N]

    prep_codebook<<<K_CODES, 64, 0, stream>>>(w, wn, msw, wf);
    vq_main_kernel<<<N_ROWS / ROWS_PER_BLOCK, 256, 0, stream>>>(
        x, wn, msw, wf, out_q, out_idx, partial);
    finalize_kernel<<<1, 256, 0, stream>>>(partial, out_loss);
}